// Round 11
// baseline (243.310 us; speedup 1.0000x reference)
//
#include <hip/hip_runtime.h>
#include <cstdint>
#include <cstddef>

typedef unsigned short ushort_t;
typedef __attribute__((ext_vector_type(4))) float f32x4;
typedef __attribute__((ext_vector_type(8))) short s16x8;

#define PI_4F 0.78539816339744830962f

// round-to-nearest-even fp32 -> bf16
__device__ inline ushort_t f2bf(float f) {
  unsigned int u = __float_as_uint(f);
  u = u + 0x7fffu + ((u >> 16) & 1u);
  return (ushort_t)(u >> 16);
}

// ---------------------------------------------------------------------------
// rot matrix for one (b, n): fills M[81] (unscaled).
// ---------------------------------------------------------------------------
__device__ void rot_compute(float t, float s, float* M) {
  float xv = cosf(t) * s, yv = sinf(t) * s;
  bool pos = (t >= 0.0f), big = (s >= 1.0f), m1 = (fabsf(t) <= PI_4F);
#pragma unroll
  for (int i = 0; i < 81; ++i) M[i] = 0.0f;
  M[36 + 4] = 1.0f;
  if (pos) {
    float a = xv - yv, bb = xv * yv, c = xv + yv;
    if (m1 && big) {  // pb1
      M[0] = a; M[1] = 1 - a;
      M[9 + 1] = 1 - yv; M[9 + 2] = yv;
      M[18 + 2] = a; M[18 + 5] = 1 - a;
      M[27 + 0] = yv; M[27 + 3] = 1 - yv;
      M[45 + 5] = 1 - yv; M[45 + 8] = yv;
      M[54 + 3] = 1 - a; M[54 + 6] = a;
      M[63 + 6] = yv; M[63 + 7] = 1 - yv;
      M[72 + 7] = 1 - a; M[72 + 8] = a;
    } else if (m1) {  // ps1
      float d = a * c, e = a + c;
      M[0] = d; M[1] = a - d; M[3] = c - d; M[4] = 1 - e + d;
      M[9 + 1] = xv - bb; M[9 + 2] = bb; M[9 + 4] = 1 - c + bb; M[9 + 5] = yv - bb;
      M[18 + 1] = c - d; M[18 + 2] = d; M[18 + 4] = 1 - e + d; M[18 + 5] = a - d;
      M[27 + 0] = bb; M[27 + 1] = yv - bb; M[27 + 3] = xv - bb; M[27 + 4] = 1 - c + bb;
      M[45 + 4] = 1 - c + bb; M[45 + 5] = xv - bb; M[45 + 7] = yv - bb; M[45 + 8] = bb;
      M[54 + 3] = a - d; M[54 + 4] = 1 - e + d; M[54 + 6] = d; M[54 + 7] = c - d;
      M[63 + 3] = yv - bb; M[63 + 4] = 1 - c + bb; M[63 + 6] = bb; M[63 + 7] = xv - bb;
      M[72 + 4] = 1 - e + d; M[72 + 5] = c - d; M[72 + 7] = a - d; M[72 + 8] = d;
    } else {  // pb2 == ps2
      M[0] = a; M[1] = 1 - a;
      M[9 + 1] = xv - bb; M[9 + 2] = bb; M[9 + 4] = 1 - c + bb; M[9 + 5] = yv - bb;
      M[18 + 2] = a; M[18 + 5] = 1 - a;
      M[27 + 0] = bb; M[27 + 1] = yv - bb; M[27 + 3] = xv - bb; M[27 + 4] = 1 - c + bb;
      M[45 + 4] = 1 - c + bb; M[45 + 5] = xv - bb; M[45 + 7] = yv - bb; M[45 + 8] = bb;
      M[54 + 3] = 1 - a; M[54 + 6] = a;
      M[63 + 3] = yv - bb; M[63 + 4] = 1 - c + bb; M[63 + 6] = bb; M[63 + 7] = xv - bb;
      M[72 + 7] = 1 - a; M[72 + 8] = a;
    }
  } else {
    float yp = -yv;
    float ap = xv - yp, bp = xv * yp, cp = xv + yp;
    if (m1 && big) {  // nb1
      M[0] = cp; M[3] = 1 - cp;
      M[9 + 0] = yp; M[9 + 1] = 1 - yp;
      M[18 + 1] = 1 - cp; M[18 + 2] = cp;
      M[27 + 3] = 1 - yp; M[27 + 6] = yp;
      M[45 + 2] = yp; M[45 + 5] = 1 - yp;
      M[54 + 6] = cp; M[54 + 7] = 1 - cp;
      M[63 + 7] = 1 - yp; M[63 + 8] = yp;
      M[72 + 5] = 1 - cp; M[72 + 8] = cp;
    } else if (m1) {  // ns1
      float dp = ap * cp, ep = ap + cp;
      M[0] = dp; M[1] = cp - dp; M[3] = ap - dp; M[4] = 1 - ep + dp;
      M[9 + 0] = bp; M[9 + 1] = xv - bp; M[9 + 3] = yp - bp; M[9 + 4] = 1 - cp + bp;
      M[18 + 1] = ap - dp; M[18 + 2] = dp; M[18 + 4] = 1 - ep + dp; M[18 + 5] = cp - dp;
      M[27 + 1] = yp - bp; M[27 + 2] = bp; M[27 + 4] = 1 - cp + bp; M[27 + 5] = xv - bp;
      M[45 + 3] = xv - bp; M[45 + 4] = 1 - cp + bp; M[45 + 6] = bp; M[45 + 7] = yp - bp;
      M[54 + 3] = cp - dp; M[54 + 4] = 1 - ep + dp; M[54 + 6] = dp; M[54 + 7] = ap - dp;
      M[63 + 4] = 1 - cp + bp; M[63 + 5] = yp - bp; M[63 + 7] = xv - bp; M[63 + 8] = bp;
      M[72 + 4] = 1 - ep + dp; M[72 + 5] = ap - dp; M[72 + 7] = cp - dp; M[72 + 8] = dp;
    } else {  // nb2 == ns2
      M[0] = cp; M[3] = 1 - cp;
      M[9 + 0] = bp; M[9 + 1] = xv - bp; M[9 + 3] = yp - bp; M[9 + 4] = 1 - cp + bp;
      M[18 + 1] = 1 - cp; M[18 + 2] = cp;
      M[27 + 3] = xv - bp; M[27 + 4] = 1 - cp + bp; M[27 + 6] = bp; M[27 + 7] = yp - bp;
      M[45 + 1] = yp - bp; M[45 + 2] = bp; M[45 + 4] = 1 - cp + bp; M[45 + 5] = xv - bp;
      M[54 + 6] = cp; M[54 + 7] = 1 - cp;
      M[63 + 4] = 1 - cp + bp; M[63 + 5] = yp - bp; M[63 + 7] = xv - bp; M[63 + 8] = bp;
      M[72 + 5] = 1 - cp; M[72 + 8] = cp;
    }
  }
}

// ---------------------------------------------------------------------------
// Fused prep kernel (unchanged from R5, proven).
//   blocks 0..255    = wt: block (o2, bq): o = {o2*2, o2*2+1}, b = bq*8..+7.
//   blocks 256..4351 = transpose: x [b][c][h][w] fp32 -> xpad bf16 + borders.
// ---------------------------------------------------------------------------
__global__ __launch_bounds__(256) void prep_kernel(
    const float* __restrict__ x, const float* __restrict__ weight,
    const float* __restrict__ thetas, const float* __restrict__ scales,
    const float* __restrict__ lambdas, ushort_t* __restrict__ xpad,
    ushort_t* __restrict__ wtout) {
  __shared__ __align__(16) char smem[32 * 81 * 4];  // 10368 B >= transpose's 8704
  const int bi = blockIdx.x;
  const int t = threadIdx.x;

  if (bi < 256) {
    // ---- weight-transform part ----
    float* rotl = (float*)smem;  // [32][81]
    const int o2 = bi & 127, bq = bi >> 7;  // bq in 0..1 -> 8 b each
    const int half = t >> 7, tloc = t & 127;
    const int o = o2 * 2 + half;
    const int c = tloc * 2;
    float wv0[4][9], wv1[4][9];
#pragma unroll
    for (int n = 0; n < 4; ++n) {
      const float* wp = weight + (((size_t)(n * 256 + o)) * 256 + c) * 9;
#pragma unroll
      for (int j = 0; j < 9; ++j) { wv0[n][j] = wp[j]; wv1[n][j] = wp[9 + j]; }
    }
    if (t < 32) {
      int gid = bq * 32 + t;  // (b*4 + n) for b = bq*8 + t/4, n = t%4
      float M[81];
      rot_compute(thetas[gid], scales[gid], M);
      float lam = lambdas[gid];
#pragma unroll
      for (int i = 0; i < 81; ++i) rotl[t * 81 + i] = M[i] * lam;
    }
    __syncthreads();
#pragma unroll
    for (int bl = 0; bl < 8; ++bl) {
      const int b = bq * 8 + bl;
#pragma unroll
      for (int i = 0; i < 9; ++i) {
        float a0 = 0.0f, a1 = 0.0f;
#pragma unroll
        for (int n = 0; n < 4; ++n) {
          const float* r = &rotl[(bl * 4 + n) * 81 + i * 9];
#pragma unroll
          for (int j = 0; j < 9; ++j) {
            a0 = fmaf(r[j], wv0[n][j], a0);
            a1 = fmaf(r[j], wv1[n][j], a1);
          }
        }
        unsigned int word = (unsigned int)f2bf(a0) | ((unsigned int)f2bf(a1) << 16);
        *(unsigned int*)&wtout[((size_t)((b * 9 + i) * 256 + o)) * 256 + c] = word;
      }
    }
  } else {
    // ---- transpose part ----
    ushort_t (*tile)[68] = (ushort_t(*)[68])smem;
    const int bi2 = bi - 256;
    const int b = bi2 >> 8, ct = (bi2 >> 6) & 3, st = bi2 & 63;
    const int c0 = ct * 64;
    const float* xb = x + ((size_t)(b * 256 + c0)) * 4096 + st * 64;
#pragma unroll
    for (int k = 0; k < 4; ++k) {
      int idx = t + 256 * k;            // (c_l 0..63) x (w4 0,4,..60)
      int c_l = idx >> 4, w4 = (idx & 15) * 4;
      float4 v = *(const float4*)&xb[(size_t)c_l * 4096 + w4];
      tile[w4 + 0][c_l] = f2bf(v.x);
      tile[w4 + 1][c_l] = f2bf(v.y);
      tile[w4 + 2][c_l] = f2bf(v.z);
      tile[w4 + 3][c_l] = f2bf(v.w);
    }
    __syncthreads();
    const int c4 = (t & 15) * 4, wl = t >> 4;
    const size_t rowbase = (size_t)(b * 4356 + (st + 1) * 66) * 256 + c0;
#pragma unroll
    for (int k = 0; k < 4; ++k) {
      int w = wl + 16 * k;
      uint2 v = *(const uint2*)&tile[w][c4];
      *(uint2*)&xpad[rowbase + (size_t)(w + 1) * 256 + c4] = v;
    }
    // fused border zeroing
    if (t < 32) {
      int w = (t & 16) ? 65 : 0;
      int cc = (t & 15) * 4;
      *(uint2*)&xpad[rowbase + (size_t)w * 256 + cc] = make_uint2(0u, 0u);
    }
    if (st == 0 || st == 63) {
      const int h = (st == 0) ? 0 : 65;
      const size_t hb = (size_t)(b * 4356 + h * 66) * 256 + c0;
      for (int idx = t; idx < 66 * 16; idx += 256) {
        int w = idx >> 4, cc = (idx & 15) * 4;
        *(uint2*)&xpad[hb + (size_t)w * 256 + cc] = make_uint2(0u, 0u);
      }
    }
  }
}

// ---------------------------------------------------------------------------
// Kernel 3: implicit-GEMM conv, bf16 MFMA 16x16x32 on the PROVEN R9 geometry
// (256 o x 256 hw, 512 thr / 8 waves of 128x64, 1 block/CU, 3-stage LDS ring,
// raw s_barrier + counted vmcnt(4), identical buffer layout / cg8 / aoff/boff
// — 0 bank conflicts measured).
// NEW: cross-step register fragment prefetch, PINNED with T19
// sched_group_barrier. Per step after WAITB: {4 gload_lds (tile ks+3)} ->
// {12 ds_read (frags ks+1 -> alternate reg set)} -> {32 MFMA (frags ks, regs)}.
// R4 proved the unpinned form gets its fragloads SUNK by the scheduler back
// to the use sites (VGPR stayed 108), recreating the LDS-burst/MFMA-burst
// serialization that R9's counters show (LDS 1024 + matrix 1242 ~= 2577
// cyc/step wall). Pinning issues the ds_reads a full step (~2500 cyc) ahead
// of their lgkm waits -> waits are free -> step ~= max(pipes), not sum.
// Ring/vmcnt algebra: 3 stages in flight; at each WAITB entry 8 outstanding,
// drain to 4 -> stage(ks+1) resident exactly when fragload(ks+1) needs it;
// stage(ks+3) overwrites buf[ks%3] whose last reads drained at this WAITB's
// lgkmcnt(0) BEFORE the barrier. Tail ks=69..71 stages clamp to tile 71 into
// dead buffers; final fragload lands in an unused reg set. All 72 traced.
// ---------------------------------------------------------------------------
__device__ inline void gload16(const ushort_t* g, ushort_t* l) {
  __builtin_amdgcn_global_load_lds(
      (const __attribute__((address_space(1))) unsigned int*)g,
      (__attribute__((address_space(3))) unsigned int*)l, 16, 0, 0);
}

#define WAITB(N)                                                      \
  asm volatile("s_waitcnt vmcnt(" #N ") lgkmcnt(0)\n\ts_barrier" ::: "memory")

// step ks: stage tile KS3 -> (AD,BD)=buf[ks%3]; fragload frags(ks+1) from
// (AN,BN)=buf[(ks+1)%3] into next set; MFMA from current set. Emission order
// pinned: 4 VMEM_READ, 12 DS_READ, 32 MFMA.
#define STEP(KS3, AN, BN, AD, BD, AFC, BFC, AFN, BFN)                 \
  WAITB(4);                                                           \
  __builtin_amdgcn_sched_barrier(0);                                  \
  stage((KS3) > 71 ? 71 : (KS3), AD, BD);                             \
  fragload(AN, BN, AFN, BFN);                                         \
  mfma_step(AFC, BFC);                                                \
  __builtin_amdgcn_sched_group_barrier(0x020, 4, 0);  /* VMEM_READ */ \
  __builtin_amdgcn_sched_group_barrier(0x100, 12, 0); /* DS_READ  */  \
  __builtin_amdgcn_sched_group_barrier(0x008, 32, 0); /* MFMA     */

__global__ __launch_bounds__(512, 2) void conv_kernel(
    const ushort_t* __restrict__ xpad, const ushort_t* __restrict__ wt,
    float* __restrict__ out) {
  // six statically distinct LDS objects (3-stage ring), 16 KB each
  __shared__ __align__(16) ushort_t As0[8192], As1[8192], As2[8192];
  __shared__ __align__(16) ushort_t Bs0[8192], Bs1[8192], Bs2[8192];

  const int id = blockIdx.x;            // 0..255
  const int xcd = id & 7;
  const int jj = id >> 3;               // 0..31 within XCD
  const int b = xcd * 2 + (jj >> 4);    // 2 batches per XCD
  const int ntile = jj & 15;            // 16 hw-tiles of 256 (4 h-rows)

  const int t = threadIdx.x;            // 0..511
  const int wave = t >> 6, lane = t & 63;
  const int wm = wave & 1, wn = wave >> 1;   // wave tile: 128 o x 64 hw
  const int lr = lane & 15, lq = lane >> 4;
  const int h0 = ntile * 4;

  const ushort_t* wt_b = wt + (size_t)b * 589824;     // 9*256*256
  const ushort_t* xp_b = xpad + (size_t)b * 1115136;  // 4356*256

  const int lrow = t >> 2;                           // 0..127
  const int cg8 = (((t & 3) ^ ((t >> 3) & 3)) * 8);  // swizzled global 16B chunk
  const int rsw = (lr >> 1) & 3;
  const int aoff = (wm * 128 + lr) * 32 + ((lq ^ rsw) * 8);
  const int boff = (wn * 64 + lr) * 32 + ((lq ^ rsw) * 8);

  f32x4 acc[8][4];
#pragma unroll
  for (int i = 0; i < 8; ++i)
#pragma unroll
    for (int j2 = 0; j2 < 4; ++j2) acc[i][j2] = (f32x4)(0.0f);

  s16x8 afA[8], bfA[4], afB[8], bfB[4];  // double-buffered fragment sets

  auto stage = [&](int ks, ushort_t* Ad, ushort_t* Bd) {
    const int tap = ks >> 3;
    const int c0k = (ks & 7) << 5;
    const int kh = tap / 3, kw = tap - kh * 3;
    const ushort_t* ga = wt_b + ((size_t)(tap * 256 + lrow)) * 256 + c0k + cg8;
    gload16(ga, Ad + wave * 512);
    gload16(ga + 128 * 256, Ad + 4096 + wave * 512);
    const int sp = (h0 + (lrow >> 6) + kh) * 66 + kw + (lrow & 63);
    gload16(xp_b + (size_t)sp * 256 + c0k + cg8, Bd + wave * 512);
    gload16(xp_b + (size_t)(sp + 132) * 256 + c0k + cg8, Bd + 4096 + wave * 512);
  };

  auto fragload = [&](const ushort_t* Ab, const ushort_t* Bb, s16x8* af, s16x8* bf) {
#pragma unroll
    for (int ni = 0; ni < 4; ++ni) bf[ni] = *(const s16x8*)(Bb + boff + ni * 512);
#pragma unroll
    for (int mi = 0; mi < 8; ++mi) af[mi] = *(const s16x8*)(Ab + aoff + mi * 512);
  };

  auto mfma_step = [&](const s16x8* af, const s16x8* bf) {
#pragma unroll
    for (int mi = 0; mi < 8; ++mi)
#pragma unroll
      for (int ni = 0; ni < 4; ++ni)
        acc[mi][ni] = __builtin_amdgcn_mfma_f32_16x16x32_bf16(af[mi], bf[ni], acc[mi][ni], 0, 0, 0);
  };

  // prologue: 3 stages in flight; drain to stage0,1 resident; preload frags(0)
  stage(0, As0, Bs0);
  stage(1, As1, Bs1);
  stage(2, As2, Bs2);
  asm volatile("s_waitcnt vmcnt(4)" ::: "memory");
  __builtin_amdgcn_s_barrier();
  fragload(As0, Bs0, afA, bfA);

  // 12 iterations x 6 steps (ring-3 x frag-parity-2); 72 K-steps total.
#pragma unroll 1
  for (int kk = 0; kk < 12; ++kk) {
    const int ks = kk * 6;
    STEP(ks + 3, As1, Bs1, As0, Bs0, afA, bfA, afB, bfB);   // step ks+0
    STEP(ks + 4, As2, Bs2, As1, Bs1, afB, bfB, afA, bfA);   // step ks+1
    STEP(ks + 5, As0, Bs0, As2, Bs2, afA, bfA, afB, bfB);   // step ks+2
    STEP(ks + 6, As1, Bs1, As0, Bs0, afB, bfB, afA, bfA);   // step ks+3
    STEP(ks + 7, As2, Bs2, As1, Bs1, afA, bfA, afB, bfB);   // step ks+4
    STEP(ks + 8, As0, Bs0, As2, Bs2, afB, bfB, afA, bfA);   // step ks+5
  }

  // Epilogue. C/D layout (m89): col(n) = lane&15, row(m) = (lane>>4)*4 + reg
  float* ob = out + ((size_t)(b * 256 + wm * 128)) * 4096 + ntile * 256 + wn * 64 + lr;
#pragma unroll
  for (int mi = 0; mi < 8; ++mi)
#pragma unroll
    for (int r = 0; r < 4; ++r) {
      float* orow = ob + (size_t)(mi * 16 + lq * 4 + r) * 4096;
#pragma unroll
      for (int ni = 0; ni < 4; ++ni) orow[ni * 16] = acc[mi][ni][r];
    }
}

// ---------------------------------------------------------------------------
extern "C" void kernel_launch(void* const* d_in, const int* in_sizes, int n_in,
                              void* d_out, int out_size, void* d_ws, size_t ws_size,
                              hipStream_t stream) {
  const float* x = (const float*)d_in[0];       // [16,256,64,64]
  const float* thetas = (const float*)d_in[1];  // [16,4]
  const float* scales = (const float*)d_in[2];  // [16,4]
  const float* lambdas = (const float*)d_in[3]; // [16,4]
  const float* weight = (const float*)d_in[4];  // [4,256,256,3,3]
  float* out = (float*)d_out;                   // [16,256,64,64]

  // workspace layout:
  //   Wt   bf16 [16][9][256][256]   @ 0         (18874368 B)
  //   xpad bf16 [16][66][66][256]   @ 18874368  (35684352 B)
  ushort_t* wt_ws = (ushort_t*)d_ws;
  ushort_t* xpad_ws = (ushort_t*)((char*)d_ws + 18874368);

  prep_kernel<<<4352, 256, 0, stream>>>(x, weight, thetas, scales, lambdas,
                                        xpad_ws, wt_ws);
  conv_kernel<<<256, 512, 0, stream>>>(xpad_ws, wt_ws, out);
}

// Round 12
// 204.281 us; speedup vs baseline: 1.1911x; 1.1911x over previous
//
#include <hip/hip_runtime.h>
#include <cstdint>
#include <cstddef>

typedef unsigned short ushort_t;
typedef __attribute__((ext_vector_type(4))) float f32x4;
typedef __attribute__((ext_vector_type(8))) short s16x8;

#define PI_4F 0.78539816339744830962f

// round-to-nearest-even fp32 -> bf16
__device__ inline ushort_t f2bf(float f) {
  unsigned int u = __float_as_uint(f);
  u = u + 0x7fffu + ((u >> 16) & 1u);
  return (ushort_t)(u >> 16);
}

// ---------------------------------------------------------------------------
// rot matrix for one (b, n): fills M[81] (unscaled).
// ---------------------------------------------------------------------------
__device__ void rot_compute(float t, float s, float* M) {
  float xv = cosf(t) * s, yv = sinf(t) * s;
  bool pos = (t >= 0.0f), big = (s >= 1.0f), m1 = (fabsf(t) <= PI_4F);
#pragma unroll
  for (int i = 0; i < 81; ++i) M[i] = 0.0f;
  M[36 + 4] = 1.0f;
  if (pos) {
    float a = xv - yv, bb = xv * yv, c = xv + yv;
    if (m1 && big) {  // pb1
      M[0] = a; M[1] = 1 - a;
      M[9 + 1] = 1 - yv; M[9 + 2] = yv;
      M[18 + 2] = a; M[18 + 5] = 1 - a;
      M[27 + 0] = yv; M[27 + 3] = 1 - yv;
      M[45 + 5] = 1 - yv; M[45 + 8] = yv;
      M[54 + 3] = 1 - a; M[54 + 6] = a;
      M[63 + 6] = yv; M[63 + 7] = 1 - yv;
      M[72 + 7] = 1 - a; M[72 + 8] = a;
    } else if (m1) {  // ps1
      float d = a * c, e = a + c;
      M[0] = d; M[1] = a - d; M[3] = c - d; M[4] = 1 - e + d;
      M[9 + 1] = xv - bb; M[9 + 2] = bb; M[9 + 4] = 1 - c + bb; M[9 + 5] = yv - bb;
      M[18 + 1] = c - d; M[18 + 2] = d; M[18 + 4] = 1 - e + d; M[18 + 5] = a - d;
      M[27 + 0] = bb; M[27 + 1] = yv - bb; M[27 + 3] = xv - bb; M[27 + 4] = 1 - c + bb;
      M[45 + 4] = 1 - c + bb; M[45 + 5] = xv - bb; M[45 + 7] = yv - bb; M[45 + 8] = bb;
      M[54 + 3] = a - d; M[54 + 4] = 1 - e + d; M[54 + 6] = d; M[54 + 7] = c - d;
      M[63 + 3] = yv - bb; M[63 + 4] = 1 - c + bb; M[63 + 6] = bb; M[63 + 7] = xv - bb;
      M[72 + 4] = 1 - e + d; M[72 + 5] = c - d; M[72 + 7] = a - d; M[72 + 8] = d;
    } else {  // pb2 == ps2
      M[0] = a; M[1] = 1 - a;
      M[9 + 1] = xv - bb; M[9 + 2] = bb; M[9 + 4] = 1 - c + bb; M[9 + 5] = yv - bb;
      M[18 + 2] = a; M[18 + 5] = 1 - a;
      M[27 + 0] = bb; M[27 + 1] = yv - bb; M[27 + 3] = xv - bb; M[27 + 4] = 1 - c + bb;
      M[45 + 4] = 1 - c + bb; M[45 + 5] = xv - bb; M[45 + 7] = yv - bb; M[45 + 8] = bb;
      M[54 + 3] = 1 - a; M[54 + 6] = a;
      M[63 + 3] = yv - bb; M[63 + 4] = 1 - c + bb; M[63 + 6] = bb; M[63 + 7] = xv - bb;
      M[72 + 7] = 1 - a; M[72 + 8] = a;
    }
  } else {
    float yp = -yv;
    float ap = xv - yp, bp = xv * yp, cp = xv + yp;
    if (m1 && big) {  // nb1
      M[0] = cp; M[3] = 1 - cp;
      M[9 + 0] = yp; M[9 + 1] = 1 - yp;
      M[18 + 1] = 1 - cp; M[18 + 2] = cp;
      M[27 + 3] = 1 - yp; M[27 + 6] = yp;
      M[45 + 2] = yp; M[45 + 5] = 1 - yp;
      M[54 + 6] = cp; M[54 + 7] = 1 - cp;
      M[63 + 7] = 1 - yp; M[63 + 8] = yp;
      M[72 + 5] = 1 - cp; M[72 + 8] = cp;
    } else if (m1) {  // ns1
      float dp = ap * cp, ep = ap + cp;
      M[0] = dp; M[1] = cp - dp; M[3] = ap - dp; M[4] = 1 - ep + dp;
      M[9 + 0] = bp; M[9 + 1] = xv - bp; M[9 + 3] = yp - bp; M[9 + 4] = 1 - cp + bp;
      M[18 + 1] = ap - dp; M[18 + 2] = dp; M[18 + 4] = 1 - ep + dp; M[18 + 5] = cp - dp;
      M[27 + 1] = yp - bp; M[27 + 2] = bp; M[27 + 4] = 1 - cp + bp; M[27 + 5] = xv - bp;
      M[45 + 3] = xv - bp; M[45 + 4] = 1 - cp + bp; M[45 + 6] = bp; M[45 + 7] = yp - bp;
      M[54 + 3] = cp - dp; M[54 + 4] = 1 - ep + dp; M[54 + 6] = dp; M[54 + 7] = ap - dp;
      M[63 + 4] = 1 - cp + bp; M[63 + 5] = yp - bp; M[63 + 7] = xv - bp; M[63 + 8] = bp;
      M[72 + 4] = 1 - ep + dp; M[72 + 5] = ap - dp; M[72 + 7] = cp - dp; M[72 + 8] = dp;
    } else {  // nb2 == ns2
      M[0] = cp; M[3] = 1 - cp;
      M[9 + 0] = bp; M[9 + 1] = xv - bp; M[9 + 3] = yp - bp; M[9 + 4] = 1 - cp + bp;
      M[18 + 1] = 1 - cp; M[18 + 2] = cp;
      M[27 + 3] = xv - bp; M[27 + 4] = 1 - cp + bp; M[27 + 6] = bp; M[27 + 7] = yp - bp;
      M[45 + 1] = yp - bp; M[45 + 2] = bp; M[45 + 4] = 1 - cp + bp; M[45 + 5] = xv - bp;
      M[54 + 6] = cp; M[54 + 7] = 1 - cp;
      M[63 + 4] = 1 - cp + bp; M[63 + 5] = yp - bp; M[63 + 7] = xv - bp; M[63 + 8] = bp;
      M[72 + 5] = 1 - cp; M[72 + 8] = cp;
    }
  }
}

// ---------------------------------------------------------------------------
// Fused prep kernel (unchanged from R5, proven).
//   blocks 0..255    = wt: block (o2, bq): o = {o2*2, o2*2+1}, b = bq*8..+7.
//   blocks 256..4351 = transpose: x [b][c][h][w] fp32 -> xpad bf16 + borders.
// ---------------------------------------------------------------------------
__global__ __launch_bounds__(256) void prep_kernel(
    const float* __restrict__ x, const float* __restrict__ weight,
    const float* __restrict__ thetas, const float* __restrict__ scales,
    const float* __restrict__ lambdas, ushort_t* __restrict__ xpad,
    ushort_t* __restrict__ wtout) {
  __shared__ __align__(16) char smem[32 * 81 * 4];  // 10368 B >= transpose's 8704
  const int bi = blockIdx.x;
  const int t = threadIdx.x;

  if (bi < 256) {
    // ---- weight-transform part ----
    float* rotl = (float*)smem;  // [32][81]
    const int o2 = bi & 127, bq = bi >> 7;  // bq in 0..1 -> 8 b each
    const int half = t >> 7, tloc = t & 127;
    const int o = o2 * 2 + half;
    const int c = tloc * 2;
    float wv0[4][9], wv1[4][9];
#pragma unroll
    for (int n = 0; n < 4; ++n) {
      const float* wp = weight + (((size_t)(n * 256 + o)) * 256 + c) * 9;
#pragma unroll
      for (int j = 0; j < 9; ++j) { wv0[n][j] = wp[j]; wv1[n][j] = wp[9 + j]; }
    }
    if (t < 32) {
      int gid = bq * 32 + t;  // (b*4 + n) for b = bq*8 + t/4, n = t%4
      float M[81];
      rot_compute(thetas[gid], scales[gid], M);
      float lam = lambdas[gid];
#pragma unroll
      for (int i = 0; i < 81; ++i) rotl[t * 81 + i] = M[i] * lam;
    }
    __syncthreads();
#pragma unroll
    for (int bl = 0; bl < 8; ++bl) {
      const int b = bq * 8 + bl;
#pragma unroll
      for (int i = 0; i < 9; ++i) {
        float a0 = 0.0f, a1 = 0.0f;
#pragma unroll
        for (int n = 0; n < 4; ++n) {
          const float* r = &rotl[(bl * 4 + n) * 81 + i * 9];
#pragma unroll
          for (int j = 0; j < 9; ++j) {
            a0 = fmaf(r[j], wv0[n][j], a0);
            a1 = fmaf(r[j], wv1[n][j], a1);
          }
        }
        unsigned int word = (unsigned int)f2bf(a0) | ((unsigned int)f2bf(a1) << 16);
        *(unsigned int*)&wtout[((size_t)((b * 9 + i) * 256 + o)) * 256 + c] = word;
      }
    }
  } else {
    // ---- transpose part ----
    ushort_t (*tile)[68] = (ushort_t(*)[68])smem;
    const int bi2 = bi - 256;
    const int b = bi2 >> 8, ct = (bi2 >> 6) & 3, st = bi2 & 63;
    const int c0 = ct * 64;
    const float* xb = x + ((size_t)(b * 256 + c0)) * 4096 + st * 64;
#pragma unroll
    for (int k = 0; k < 4; ++k) {
      int idx = t + 256 * k;            // (c_l 0..63) x (w4 0,4,..60)
      int c_l = idx >> 4, w4 = (idx & 15) * 4;
      float4 v = *(const float4*)&xb[(size_t)c_l * 4096 + w4];
      tile[w4 + 0][c_l] = f2bf(v.x);
      tile[w4 + 1][c_l] = f2bf(v.y);
      tile[w4 + 2][c_l] = f2bf(v.z);
      tile[w4 + 3][c_l] = f2bf(v.w);
    }
    __syncthreads();
    const int c4 = (t & 15) * 4, wl = t >> 4;
    const size_t rowbase = (size_t)(b * 4356 + (st + 1) * 66) * 256 + c0;
#pragma unroll
    for (int k = 0; k < 4; ++k) {
      int w = wl + 16 * k;
      uint2 v = *(const uint2*)&tile[w][c4];
      *(uint2*)&xpad[rowbase + (size_t)(w + 1) * 256 + c4] = v;
    }
    // fused border zeroing
    if (t < 32) {
      int w = (t & 16) ? 65 : 0;
      int cc = (t & 15) * 4;
      *(uint2*)&xpad[rowbase + (size_t)w * 256 + cc] = make_uint2(0u, 0u);
    }
    if (st == 0 || st == 63) {
      const int h = (st == 0) ? 0 : 65;
      const size_t hb = (size_t)(b * 4356 + h * 66) * 256 + c0;
      for (int idx = t; idx < 66 * 16; idx += 256) {
        int w = idx >> 4, cc = (idx & 15) * 4;
        *(uint2*)&xpad[hb + (size_t)w * 256 + cc] = make_uint2(0u, 0u);
      }
    }
  }
}

// ---------------------------------------------------------------------------
// Kernel 3: implicit-GEMM conv, bf16 MFMA 16x16x32. PROVEN BEST (R9, 77 us,
// 1005 TF, 41-43% MfmaUtil, 0 bank conflicts): R2 sync template (3-stage
// ring, raw s_barrier + counted vmcnt, never 0 in loop) at 256 o x 256 hw,
// 512 threads (8 waves of 128x64), grid 256 = exactly 1 block/CU.
// Structure-edit ledger 0-for-8 (setprio, reg-pipeline, phase-split, reg-A,
// 32x32 shape, 8-phase port, T19 pin all regressed) — this template + this
// geometry is the measured optimum for this op.
// vmcnt: 4 loads/thread/stage -> WAITB(4); tail 4 -> 0.
// LDS 6 x 16 KB = 96 KB -> 1 block/CU, zero tail.
// ---------------------------------------------------------------------------
__device__ inline void gload16(const ushort_t* g, ushort_t* l) {
  __builtin_amdgcn_global_load_lds(
      (const __attribute__((address_space(1))) unsigned int*)g,
      (__attribute__((address_space(3))) unsigned int*)l, 16, 0, 0);
}

#define WAITB(N)                                                      \
  asm volatile("s_waitcnt vmcnt(" #N ") lgkmcnt(0)\n\ts_barrier" ::: "memory")

__global__ __launch_bounds__(512, 2) void conv_kernel(
    const ushort_t* __restrict__ xpad, const ushort_t* __restrict__ wt,
    float* __restrict__ out) {
  // six statically distinct LDS objects (3-stage ring), 16 KB each
  __shared__ __align__(16) ushort_t As0[8192], As1[8192], As2[8192];
  __shared__ __align__(16) ushort_t Bs0[8192], Bs1[8192], Bs2[8192];

  const int id = blockIdx.x;            // 0..255
  const int xcd = id & 7;
  const int jj = id >> 3;               // 0..31 within XCD
  const int b = xcd * 2 + (jj >> 4);    // 2 batches per XCD
  const int ntile = jj & 15;            // 16 hw-tiles of 256 (4 h-rows)

  const int t = threadIdx.x;            // 0..511
  const int wave = t >> 6, lane = t & 63;
  const int wm = wave & 1, wn = wave >> 1;   // wave tile: 128 o x 64 hw (wn 0..3)
  const int lr = lane & 15, lq = lane >> 4;
  const int h0 = ntile * 4;

  const ushort_t* wt_b = wt + (size_t)b * 589824;     // 9*256*256
  const ushort_t* xp_b = xpad + (size_t)b * 1115136;  // 4356*256

  const int lrow = t >> 2;                           // 0..127
  const int cg8 = (((t & 3) ^ ((t >> 3) & 3)) * 8);  // swizzled global 16B chunk
  const int rsw = (lr >> 1) & 3;
  const int aoff = (wm * 128 + lr) * 32 + ((lq ^ rsw) * 8);
  const int boff = (wn * 64 + lr) * 32 + ((lq ^ rsw) * 8);

  f32x4 acc[8][4];
#pragma unroll
  for (int i = 0; i < 8; ++i)
#pragma unroll
    for (int j2 = 0; j2 < 4; ++j2) acc[i][j2] = (f32x4)(0.0f);

  auto stage = [&](int ks, ushort_t* Ad, ushort_t* Bd) {
    const int tap = ks >> 3;
    const int c0k = (ks & 7) << 5;
    const int kh = tap / 3, kw = tap - kh * 3;
    // A: Wt[b][tap][o 0..255][c0k..+31]; rows lrow, lrow+128 (8 waves cover 128)
    const ushort_t* ga = wt_b + ((size_t)(tap * 256 + lrow)) * 256 + c0k + cg8;
    gload16(ga, Ad + wave * 512);
    gload16(ga + 128 * 256, Ad + 4096 + wave * 512);
    // B: n = lrow (0..127) and lrow+128 -> spatial (h0 + n/64 + kh, n%64 + kw)
    const int sp = (h0 + (lrow >> 6) + kh) * 66 + kw + (lrow & 63);
    gload16(xp_b + (size_t)sp * 256 + c0k + cg8, Bd + wave * 512);
    gload16(xp_b + (size_t)(sp + 132) * 256 + c0k + cg8, Bd + 4096 + wave * 512);
  };

  auto compute = [&](const ushort_t* Ab, const ushort_t* Bb) {
    s16x8 bfr[4];
#pragma unroll
    for (int ni = 0; ni < 4; ++ni)
      bfr[ni] = *(const s16x8*)(Bb + boff + ni * 512);
#pragma unroll
    for (int mi = 0; mi < 8; ++mi) {
      s16x8 af = *(const s16x8*)(Ab + aoff + mi * 512);
#pragma unroll
      for (int ni = 0; ni < 4; ++ni)
        acc[mi][ni] = __builtin_amdgcn_mfma_f32_16x16x32_bf16(af, bfr[ni], acc[mi][ni], 0, 0, 0);
    }
  };

  stage(0, As0, Bs0);
  stage(1, As1, Bs1);

  // 23 unrolled triples: compute ks = 0..68, stage through ks = 70.
#pragma unroll 1
  for (int kk = 0; kk < 23; ++kk) {
    const int ks = kk * 3;
    WAITB(4);                      // stage(ks) resident; stage(ks+1) in flight
    stage(ks + 2, As2, Bs2);
    compute(As0, Bs0);
    WAITB(4);
    stage(ks + 3, As0, Bs0);
    compute(As1, Bs1);
    WAITB(4);
    stage(ks + 4, As1, Bs1);
    compute(As2, Bs2);
  }
  // tail: outstanding = stage69 (As0), stage70 (As1)
  WAITB(4);                        // stage69 resident
  stage(71, As2, Bs2);
  compute(As0, Bs0);               // ks = 69
  WAITB(4);                        // stage70 resident (71's 4 in flight)
  compute(As1, Bs1);               // ks = 70
  WAITB(0);                        // full drain
  compute(As2, Bs2);               // ks = 71

  // Epilogue. C/D layout (m89): col(n) = lane&15, row(m) = (lane>>4)*4 + reg
  float* ob = out + ((size_t)(b * 256 + wm * 128)) * 4096 + ntile * 256 + wn * 64 + lr;
#pragma unroll
  for (int mi = 0; mi < 8; ++mi)
#pragma unroll
    for (int r = 0; r < 4; ++r) {
      float* orow = ob + (size_t)(mi * 16 + lq * 4 + r) * 4096;
#pragma unroll
      for (int ni = 0; ni < 4; ++ni) orow[ni * 16] = acc[mi][ni][r];
    }
}

// ---------------------------------------------------------------------------
extern "C" void kernel_launch(void* const* d_in, const int* in_sizes, int n_in,
                              void* d_out, int out_size, void* d_ws, size_t ws_size,
                              hipStream_t stream) {
  const float* x = (const float*)d_in[0];       // [16,256,64,64]
  const float* thetas = (const float*)d_in[1];  // [16,4]
  const float* scales = (const float*)d_in[2];  // [16,4]
  const float* lambdas = (const float*)d_in[3]; // [16,4]
  const float* weight = (const float*)d_in[4];  // [4,256,256,3,3]
  float* out = (float*)d_out;                   // [16,256,64,64]

  // workspace layout:
  //   Wt   bf16 [16][9][256][256]   @ 0         (18874368 B)
  //   xpad bf16 [16][66][66][256]   @ 18874368  (35684352 B)
  ushort_t* wt_ws = (ushort_t*)d_ws;
  ushort_t* xpad_ws = (ushort_t*)((char*)d_ws + 18874368);

  prep_kernel<<<4352, 256, 0, stream>>>(x, weight, thetas, scales, lambdas,
                                        xpad_ws, wt_ws);
  conv_kernel<<<256, 512, 0, stream>>>(xpad_ws, wt_ws, out);
}